// Round 12
// baseline (61.229 us; speedup 1.0000x reference)
//
#include <hip/hip_runtime.h>
#include <hip/hip_bf16.h>
#include <hip/hip_fp16.h>

#define N_  4
#define C_  64
#define H_  28
#define W_  60
#define ZC_ 200
#define YC_ 8
#define XC_ 200
#define OUTC_ 128
#define KD_ 512            // C_*YC_
#define EPS_ 1e-6f
#define ZB 4               // z slices per block
#define XB 8               // x positions per block
#define NCOL 32            // ZB*XB columns per block

typedef __attribute__((ext_vector_type(8))) short short8;
typedef __attribute__((ext_vector_type(4))) float f32x4;

__device__ __forceinline__ unsigned short f2bf(float f) {
    unsigned int u = __float_as_uint(f);
    u += 0x7FFF + ((u >> 16) & 1);   // round-to-nearest-even
    return (unsigned short)(u >> 16);
}

// ---------------------------------------------------------------------------
// Prep: featB[n][h][w][c] = bf16(img[n][c][h][w])  (channels-last, bf16)
//       Wb[o][y*64+c]     = bf16(W[o][c*8+y])      (y-major k, bf16)
// ---------------------------------------------------------------------------
__global__ void gsvt_prep(const float* __restrict__ img,
                          const float* __restrict__ Wc,
                          unsigned short* __restrict__ featB,
                          unsigned short* __restrict__ Wb) {
    int tid = blockIdx.x * blockDim.x + threadIdx.x;
    int stride = gridDim.x * blockDim.x;
    const int totF = N_ * H_ * W_ * C_;       // 430080
    for (int i = tid; i < totF; i += stride) {
        int c  = i & 63;
        int hw = i >> 6;
        int w  = hw % W_;
        int nh = hw / W_;
        int h  = nh % H_;
        int n  = nh / H_;
        featB[i] = f2bf(img[((n * C_ + c) * H_ + h) * W_ + w]);
    }
    const int totW = OUTC_ * KD_;             // 65536
    for (int i = tid; i < totW; i += stride) {
        int k = i & (KD_ - 1);
        int o = i >> 9;
        int y = k >> 6;
        int c = k & 63;
        Wb[i] = f2bf(Wc[o * KD_ + c * YC_ + y]);
    }
}

// float2 accumulate of one corner (8 channels in uint4), weight w broadcast.
__device__ __forceinline__ void accp(float2* n, const uint4 V, const float w) {
    float2 f0, f1, f2, f3;
    f0.x = __uint_as_float(V.x << 16); f0.y = __uint_as_float(V.x & 0xFFFF0000u);
    f1.x = __uint_as_float(V.y << 16); f1.y = __uint_as_float(V.y & 0xFFFF0000u);
    f2.x = __uint_as_float(V.z << 16); f2.y = __uint_as_float(V.z & 0xFFFF0000u);
    f3.x = __uint_as_float(V.w << 16); f3.y = __uint_as_float(V.w & 0xFFFF0000u);
    n[0].x += w * f0.x; n[0].y += w * f0.y;
    n[1].x += w * f1.x; n[1].y += w * f1.y;
    n[2].x += w * f2.x; n[2].y += w * f2.y;
    n[3].x += w * f3.x; n[3].y += w * f3.y;
}

// ===========================================================================
// 512-thread fused kernel: wave = (z-slice, y-half).  Register tables shared
// via in-wave shuffles; 4 y-iterations per wave; single barrier; GEMM with
// 8 waves x 16 rows (W read once per block).
// Grid: (25, 50), block 512.  LDS = 32 KB (redB only) -> 4 blocks/CU cap.
// ===========================================================================
__global__ __launch_bounds__(512, 4) void gsvt_fusedW(
        const float* __restrict__ coords,        // (N, ZC, YC, XC, 3)
        const float* __restrict__ validm,        // (N, ZC, YC, XC)
        const unsigned short* __restrict__ featB,// (N, H, W, C) bf16
        const unsigned short* __restrict__ Wb,   // (OUTC, 512) bf16, y-major k
        const float* __restrict__ bias,          // (OUTC)
        float* __restrict__ out)                 // (OUTC, ZC, XC)
{
    __shared__ unsigned short redB[64][NCOL][8]; // 32 KB (only LDS)

    const int z0 = blockIdx.y * ZB;
    const int x0 = blockIdx.x * XB;
    const int t  = threadIdx.x;
    const int wv = t >> 6;           // 0..7
    const int l  = t & 63;

    const int zsl = wv & 3;          // z slice of this wave
    const int yh  = wv >> 2;         // y half: 0 -> y 0..3, 1 -> y 4..7

    // ---- phase 0 (no barriers): lane owns pair (yp, xp) of slice zsl ----
    const int yp = l >> 3;
    const int xp = l & 7;
    const int zs = z0 + zsl;
    const int xg = x0 + xp;

    float gxv[4], gyv[4], gzv[4], mmv[4];
    #pragma unroll
    for (int cam = 0; cam < N_; ++cam) {
        const int cb = ((cam * ZC_ + zs) * YC_ + yp) * XC_ + xg;
        gxv[cam] = coords[cb * 3 + 0];
        gyv[cam] = coords[cb * 3 + 1];
        gzv[cam] = coords[cb * 3 + 2];
        mmv[cam] = validm[cb];
    }
    const float inv = 1.0f / (mmv[0] + mmv[1] + mmv[2] + mmv[3] + EPS_);

    // packed entry per cam: A = q00|q01<<12|q10.lo8<<24
    //                       B = q10.hi4|q11<<4|pixidx<<16|fdx<<29|fdy<<30
    unsigned Tx[4], Ty[4];
    #pragma unroll
    for (int cam = 0; cam < N_; ++cam) {
        const float xf = ((gxv[cam] + 1.0f) * (float)W_ - 1.0f) * 0.5f;
        const float yf = ((gyv[cam] + 1.0f) * (float)H_ - 1.0f) * 0.5f;
        const float zf = gzv[cam] * 0.5f;
        const float x0f = floorf(xf), y0f = floorf(yf), z0f = floorf(zf);
        const float wx = xf - x0f, wy = yf - y0f, wz = zf - z0f;
        const int xi = (int)x0f, yi = (int)y0f, zi = (int)z0f;

        const float zw = (zi == 0) ? (1.f - wz) : ((zi == -1) ? wz : 0.f);
        const float s  = mmv[cam] * zw * inv;

        const float wx0 = (xi >= 0 && xi < W_)         ? (1.f - wx) * s : 0.f;
        const float wx1 = (xi + 1 >= 0 && xi + 1 < W_) ? wx * s         : 0.f;
        const float wy0 = (yi >= 0 && yi < H_)         ? (1.f - wy)     : 0.f;
        const float wy1 = (yi + 1 >= 0 && yi + 1 < H_) ? wy             : 0.f;

        const unsigned q00 = (unsigned)(wy0 * wx0 * 4095.f + 0.5f);
        const unsigned q01 = (unsigned)(wy0 * wx1 * 4095.f + 0.5f);
        const unsigned q10 = (unsigned)(wy1 * wx0 * 4095.f + 0.5f);
        const unsigned q11 = (unsigned)(wy1 * wx1 * 4095.f + 0.5f);

        const int xc0 = min(max(xi, 0), W_ - 1);
        const int xc1 = min(max(xi + 1, 0), W_ - 1);
        const int yc0 = min(max(yi, 0), H_ - 1);
        const int yc1 = min(max(yi + 1, 0), H_ - 1);
        const unsigned pixidx = (unsigned)((cam * H_ + yc0) * W_ + xc0);  // <6720
        const unsigned fdx = (unsigned)(xc1 - xc0);   // 0/1
        const unsigned fdy = (unsigned)(yc1 - yc0);   // 0/1

        Tx[cam] = q00 | (q01 << 12) | ((q10 & 0xFFu) << 24);
        Ty[cam] = (q10 >> 8) | (q11 << 4) | (pixidx << 16)
                | (fdx << 29) | (fdy << 30);
    }

    // ---- sampling: group g owns column (zsl, g); 4 y iterations (y-half) ----
    const int g     = l >> 3;        // 0..7 column within slice
    const int lane8 = l & 7;
    const unsigned lb = (unsigned)(lane8 << 4);
    const int col   = zsl * 8 + g;   // 0..31 global column
    const char* fb  = (const char*)featB;

    #pragma unroll
    for (int i = 0; i < 4; ++i) {
        const int y   = yh * 4 + i;
        const int idx = (y << 3) | g;          // producer lane in this wave

        int ax[4], ay[4];
        #pragma unroll
        for (int cam = 0; cam < N_; ++cam) {
            ax[cam] = __shfl((int)Tx[cam], idx);
            ay[cam] = __shfl((int)Ty[cam], idx);
        }

        float2 num[4] = {{0.f,0.f},{0.f,0.f},{0.f,0.f},{0.f,0.f}};
        #pragma unroll
        for (int cam = 0; cam < N_; ++cam) {
            const unsigned A = (unsigned)ax[cam];
            const unsigned B = (unsigned)ay[cam];
            if (A | (B & 0xFFFFu)) {          // any nonzero quantized weight
                const unsigned base = (((B >> 16) & 0x1FFFu) << 7) + lb;
                const unsigned dxo  = ((B >> 29) & 1u) << 7;
                const unsigned dyo  = ((B >> 30) & 1u) * (unsigned)(W_ * 128);
                const uint4 V0 = *(const uint4*)(fb + base);
                const uint4 V1 = *(const uint4*)(fb + (base + dxo));
                const uint4 V2 = *(const uint4*)(fb + (base + dyo));
                const uint4 V3 = *(const uint4*)(fb + (base + dyo + dxo));
                const float w00 = (float)(A & 0xFFFu)                    * (1.f/4095.f);
                const float w01 = (float)((A >> 12) & 0xFFFu)            * (1.f/4095.f);
                const float w10 = (float)((A >> 24) | ((B & 0xFu) << 8)) * (1.f/4095.f);
                const float w11 = (float)((B >> 4) & 0xFFFu)             * (1.f/4095.f);
                accp(num, V0, w00);
                accp(num, V1, w01);
                accp(num, V2, w10);
                accp(num, V3, w11);
            }
        }

        unsigned r0, r1, r2, r3;
        asm("v_cvt_pk_bf16_f32 %0, %1, %2" : "=v"(r0) : "v"(num[0].x), "v"(num[0].y));
        asm("v_cvt_pk_bf16_f32 %0, %1, %2" : "=v"(r1) : "v"(num[1].x), "v"(num[1].y));
        asm("v_cvt_pk_bf16_f32 %0, %1, %2" : "=v"(r2) : "v"(num[2].x), "v"(num[2].y));
        asm("v_cvt_pk_bf16_f32 %0, %1, %2" : "=v"(r3) : "v"(num[3].x), "v"(num[3].y));

        const int kb   = y * 8 + lane8;
        const int pcol = (col & 16) | ((col ^ kb) & 15);   // XOR swizzle
        *(uint4*)&redB[kb][pcol][0] = make_uint4(r0, r1, r2, r3);
    }
    __syncthreads();   // the kernel's only barrier

    // ---- GEMM: C[128,32] = Wb[128,512] * redB[512,32]; wave owns 16 rows ----
    const int q    = l >> 4;        // 0..3
    const int l16  = l & 15;

    f32x4 acc0 = {0.f,0.f,0.f,0.f}, acc1 = {0.f,0.f,0.f,0.f};
    const unsigned short* wbase = Wb + (wv * 16 + l16) * KD_;

    #pragma unroll
    for (int ks = 0; ks < 16; ++ks) {
        const int kb = ks * 4 + q;
        const int xs = l16 ^ (kb & 15);
        const short8 Af = *(const short8*)(wbase + ks * 32 + q * 8);
        const short8 B0 = *(const short8*)&redB[kb][xs][0];
        const short8 B1 = *(const short8*)&redB[kb][16 + xs][0];
        acc0 = __builtin_amdgcn_mfma_f32_16x16x32_bf16(Af, B0, acc0, 0, 0, 0);
        acc1 = __builtin_amdgcn_mfma_f32_16x16x32_bf16(Af, B1, acc1, 0, 0, 0);
    }

    #pragma unroll
    for (int ct = 0; ct < 2; ++ct) {
        const int c2  = ct * 16 + l16;
        const int zz  = c2 >> 3;
        const int xl  = c2 & 7;
        const int ob  = (z0 + zz) * XC_ + x0 + xl;
        const f32x4 a = ct ? acc1 : acc0;
        #pragma unroll
        for (int j = 0; j < 4; ++j) {
            const int o = wv * 16 + q * 4 + j;
            out[o * (ZC_ * XC_) + ob] = a[j] + bias[o];
        }
    }
}

extern "C" void kernel_launch(void* const* d_in, const int* in_sizes, int n_in,
                              void* d_out, int out_size, void* d_ws, size_t ws_size,
                              hipStream_t stream) {
    const float* coords = (const float*)d_in[0];   // (1,4,200,8,200,3)
    const float* validm = (const float*)d_in[1];   // (1,4,200,8,200,1)
    const float* img    = (const float*)d_in[2];   // (1,4,64,28,60)
    const float* Wc     = (const float*)d_in[3];   // (128, 512)
    const float* bias   = (const float*)d_in[4];   // (128)
    float* out = (float*)d_out;                    // (1,1,128,200,200)

    unsigned short* featB = (unsigned short*)d_ws;           // 430080 bf16
    unsigned short* Wb    = featB + (N_ * H_ * W_ * C_);     // 65536 bf16

    gsvt_prep<<<512, 256, 0, stream>>>(img, Wc, featB, Wb);

    dim3 grid(XC_ / XB, ZC_ / ZB);   // (25, 50)
    gsvt_fusedW<<<grid, 512, 0, stream>>>(coords, validm, featB, Wb, bias, out);
}